// Round 1
// baseline (577.583 us; speedup 1.0000x reference)
//
#include <hip/hip_runtime.h>
#include <hip/hip_bf16.h>

typedef unsigned short u16;
typedef unsigned int u32;
typedef __attribute__((ext_vector_type(8))) short short8;
typedef __attribute__((ext_vector_type(4))) float f4;
typedef __attribute__((ext_vector_type(4))) u32 u4;

#define MFMA(a, b, c) __builtin_amdgcn_mfma_f32_16x16x32_bf16((a), (b), (c), 0, 0, 0)

// ---- constants ----
#define TT 256
#define BB 1024
#define NN (TT * BB)          // 262144 rows
#define NCHUNK (NN / 16)      // 16384 16-row chunks
// ws layout in u16 units:
#define WS_HID3 0             // N*128 bf16 frag-order (hid3, later reused as hs)
#define WS_WF   (NN * 128)    // 33554432
#define OFF_W1  0
#define OFF_W2  16384
#define OFF_W3  20480
#define OFF_WIH 24576
#define OFF_WHH 90112
#define OFF_WA  155648
#define WF_TOT  159744

static __device__ __forceinline__ u16 f2bf(float f) {
    u32 u = __float_as_uint(f);
    u32 r = (u + 0x7FFFu + ((u >> 16) & 1u)) >> 16;
    return (u16)r;
}
static __device__ __forceinline__ short8 pack8(f4 a, f4 b) {
    short8 r;
    r[0] = (short)f2bf(a[0]); r[1] = (short)f2bf(a[1]);
    r[2] = (short)f2bf(a[2]); r[3] = (short)f2bf(a[3]);
    r[4] = (short)f2bf(b[0]); r[5] = (short)f2bf(b[1]);
    r[6] = (short)f2bf(b[2]); r[7] = (short)f2bf(b[3]);
    return r;
}
static __device__ __forceinline__ short8 u4_to_s8(u4 v) {
    union { u4 u; short8 s; } t; t.u = v; return t.s;
}
static __device__ __forceinline__ float sigf(float x) {
    return __builtin_amdgcn_rcpf(1.f + __builtin_amdgcn_exp2f(-1.442695040888963f * x));
}
static __device__ __forceinline__ float tanhf_fast(float x) {
    return 2.f * __builtin_amdgcn_rcpf(1.f + __builtin_amdgcn_exp2f(-2.885390081777927f * x)) - 1.f;
}

// ---------------- K0: convert weights fp32 -> bf16 fragment order ----------------
// frag order for W[n][k] (row-major, Nn x Kd): dst[((nt*KC+kc)*64 + l)*8 + j] =
//   W[nt*16 + (l&15)][kc*32 + (l>>4)*8 + j]
static __device__ void convW128(const float* src, int Nn, u16* dst, int tid, int nth) {
    int tot = Nn * 128;
    for (int d = tid; d < tot; d += nth) {
        int j = d & 7, l = (d >> 3) & 63, ck = d >> 9;
        int kc = ck & 3, nt = ck >> 2;
        int n = nt * 16 + (l & 15), k = kc * 32 + ((l >> 4) << 3) + j;
        dst[d] = f2bf(src[n * 128 + k]);
    }
}
static __device__ void convW32(const float* src, int Nn, u16* dst, int tid, int nth) {
    int tot = Nn * 32;
    for (int d = tid; d < tot; d += nth) {
        int j = d & 7, l = (d >> 3) & 63, nt = d >> 9;
        int n = nt * 16 + (l & 15), k = ((l >> 4) << 3) + j;
        dst[d] = f2bf(src[n * 32 + k]);
    }
}

__global__ void k0_conv(const float* __restrict__ W1, const float* __restrict__ W2,
                        const float* __restrict__ W3, const float* __restrict__ Wih,
                        const float* __restrict__ Whh, const float* __restrict__ Wa,
                        const float* __restrict__ Wc, u16* __restrict__ wf) {
    int tid = blockIdx.x * blockDim.x + threadIdx.x;
    int nth = gridDim.x * blockDim.x;
    convW128(W1, 128, wf + OFF_W1, tid, nth);
    convW128(W2, 32, wf + OFF_W2, tid, nth);
    convW32(W3, 128, wf + OFF_W3, tid, nth);
    convW128(Wih, 512, wf + OFF_WIH, tid, nth);
    convW128(Whh, 512, wf + OFF_WHH, tid, nth);
    // WaWc: padded 32 x 128: rows 0..17 = Wa, 18 = Wc, 19..31 = 0
    for (int d = tid; d < 32 * 128; d += nth) {
        int j = d & 7, l = (d >> 3) & 63, ck = d >> 9;
        int kc = ck & 3, nt = ck >> 2;
        int n = nt * 16 + (l & 15), k = kc * 32 + ((l >> 4) << 3) + j;
        float v = (n < 18) ? Wa[n * 128 + k] : ((n == 18) ? Wc[k] : 0.f);
        wf[OFF_WA + d] = f2bf(v);
    }
}

// ---------------- K1: encoder (3 layers), writes hid3 bf16 frag-order ----------------
__global__ __launch_bounds__(256) void k1_enc(
    const float* __restrict__ x, const float* __restrict__ b1, const float* __restrict__ b2,
    const float* __restrict__ b3, const u16* __restrict__ wf, u16* __restrict__ hid3f) {
    __shared__ __align__(16) u16 scr[4][2560];  // per-wave: 2048 (K=128 frag) + 512 (K=32 frag)

    int tid = threadIdx.x, wv = tid >> 6, lane = tid & 63;
    int m = lane & 15, q = lane >> 4;
    u16* s1 = scr[wv];
    u16* s2 = scr[wv] + 2048;
    const short8* W1v = (const short8*)(wf + OFF_W1);
    const short8* W2v = (const short8*)(wf + OFF_W2);
    const short8* W3v = (const short8*)(wf + OFF_W3);
    int wid = blockIdx.x * 4 + wv;  // 2048 waves total

    for (int it = 0; it < 8; ++it) {
        int c = wid + it * 2048;
        // A1 frags from x (fp32 -> bf16)
        short8 a1[4];
        const float* xr = x + (size_t)(c * 16 + m) * 128 + q * 8;
#pragma unroll
        for (int kc = 0; kc < 4; ++kc) {
            f4 f0 = *(const f4*)(xr + kc * 32);
            f4 f1 = *(const f4*)(xr + kc * 32 + 4);
            a1[kc] = pack8(f0, f1);
        }
        // Layer 1: 128 -> 128
#pragma unroll
        for (int nt = 0; nt < 8; ++nt) {
            f4 acc = {0.f, 0.f, 0.f, 0.f};
#pragma unroll
            for (int kc = 0; kc < 4; ++kc) acc = MFMA(a1[kc], W1v[(nt * 4 + kc) * 64 + lane], acc);
            int col = nt * 16 + m;
            float bb = b1[col];
            int base = (col >> 5) * 512 + ((col >> 3) & 3) * 128 + (col & 7);
#pragma unroll
            for (int p = 0; p < 4; ++p) {
                float v = acc[p] + bb; v = v > 0.f ? v : 0.f;
                s1[base + (q * 4 + p) * 8] = f2bf(v);
            }
        }
        __syncthreads();
        short8 a2[4];
#pragma unroll
        for (int kc = 0; kc < 4; ++kc) a2[kc] = *(const short8*)(s1 + kc * 512 + lane * 8);
        // Layer 2: 128 -> 32
#pragma unroll
        for (int nt = 0; nt < 2; ++nt) {
            f4 acc = {0.f, 0.f, 0.f, 0.f};
#pragma unroll
            for (int kc = 0; kc < 4; ++kc) acc = MFMA(a2[kc], W2v[(nt * 4 + kc) * 64 + lane], acc);
            int col = nt * 16 + m;
            float bb = b2[col];
            int base = (col >> 3) * 128 + (col & 7);
#pragma unroll
            for (int p = 0; p < 4; ++p) {
                float v = acc[p] + bb; v = v > 0.f ? v : 0.f;
                s2[base + (q * 4 + p) * 8] = f2bf(v);
            }
        }
        __syncthreads();
        short8 a3 = *(const short8*)(s2 + lane * 8);
        // Layer 3: 32 -> 128
#pragma unroll
        for (int nt = 0; nt < 8; ++nt) {
            f4 acc = {0.f, 0.f, 0.f, 0.f};
            acc = MFMA(a3, W3v[nt * 64 + lane], acc);
            int col = nt * 16 + m;
            float bb = b3[col];
            int base = (col >> 5) * 512 + ((col >> 3) & 3) * 128 + (col & 7);
#pragma unroll
            for (int p = 0; p < 4; ++p) {
                float v = acc[p] + bb; v = v > 0.f ? v : 0.f;
                s1[base + (q * 4 + p) * 8] = f2bf(v);
            }
        }
        __syncthreads();
        u4* dst = (u4*)hid3f + (size_t)c * 256;  // (c*4+kc)*64 + lane
#pragma unroll
        for (int kc = 0; kc < 4; ++kc) dst[kc * 64 + lane] = *(const u4*)(s1 + kc * 512 + lane * 8);
    }
}

// ---------------- K3: fused LSTM scan (64 blocks x 16 batch rows, 512 thr) ----------------
__global__ __launch_bounds__(512) void k3_lstm(
    u16* __restrict__ hws,  // hid3 frags in; hs frags out (same buffer, disjoint per (t,block))
    const u16* __restrict__ wf, const float* __restrict__ bih, const float* __restrict__ bhh,
    const float* __restrict__ done, const float* __restrict__ h0, const float* __restrict__ c0) {
    __shared__ __align__(16) u16 hbuf[2][2048];  // 16 rows x 128 bf16, frag order, dbl-buffered
    __shared__ __align__(16) float dls[4096];    // (1-done) for 256 t x 16 rows

    int tid = threadIdx.x, wv = tid >> 6, lane = tid & 63;
    int u15 = lane & 15, q = lane >> 4;
    int u = wv * 16 + u15;          // this wave's hidden-unit column
    int rb = blockIdx.x * 16;       // batch-row base
    const short8* WHv = (const short8*)(wf + OFF_WHH);
    const short8* WIv = (const short8*)(wf + OFF_WIH);

    short8 wh[4][4], wi[4][4];  // b-frags resident in registers (gate g tile nt = g*8+wv)
#pragma unroll
    for (int g = 0; g < 4; ++g)
#pragma unroll
        for (int kc = 0; kc < 4; ++kc) {
            int nt = g * 8 + wv;
            wh[g][kc] = WHv[(nt * 4 + kc) * 64 + lane];
            wi[g][kc] = WIv[(nt * 4 + kc) * 64 + lane];
        }
    float bg[4];
#pragma unroll
    for (int g = 0; g < 4; ++g) bg[g] = bih[g * 128 + u] + bhh[g * 128 + u];

    for (int i = tid; i < 4096; i += 512) {
        int t = i >> 4, r = i & 15;
        dls[i] = 1.0f - done[(size_t)t * BB + rb + r];
    }
    // init h,c; lane handles rows 4q..4q+3 at column u
    float cst[4];
#pragma unroll
    for (int k = 0; k < 4; ++k) {
        int r = 4 * q + k;
        cst[k] = c0[(size_t)(rb + r) * 128 + u];
        float hv = h0[(size_t)(rb + r) * 128 + u];
        hbuf[0][(u >> 5) * 512 + (((u >> 3) & 3) * 16 + r) * 8 + (u & 7)] = f2bf(hv);
    }
    const u4* h3 = (const u4*)hws;
    u4 xf[4];
#pragma unroll
    for (int kc = 0; kc < 4; ++kc)
        xf[kc] = h3[((size_t)blockIdx.x * 4 + kc) * 64 + lane];
    __syncthreads();

    for (int t = 0; t < TT; ++t) {
        const u16* hc = hbuf[t & 1];
        u16* hn = hbuf[(t + 1) & 1];
        short8 ah[4];
#pragma unroll
        for (int kc = 0; kc < 4; ++kc) ah[kc] = *(const short8*)(hc + kc * 512 + lane * 8);
        f4 aH[4], aX[4];
#pragma unroll
        for (int g = 0; g < 4; ++g) { aH[g] = (f4){0.f, 0.f, 0.f, 0.f}; aX[g] = (f4){0.f, 0.f, 0.f, 0.f}; }
#pragma unroll
        for (int kc = 0; kc < 4; ++kc) {
            short8 xs = u4_to_s8(xf[kc]);
#pragma unroll
            for (int g = 0; g < 4; ++g) {
                aH[g] = MFMA(ah[kc], wh[g][kc], aH[g]);
                aX[g] = MFMA(xs, wi[g][kc], aX[g]);
            }
        }
        if (t < TT - 1) {
#pragma unroll
            for (int kc = 0; kc < 4; ++kc)
                xf[kc] = h3[(((size_t)(t + 1) * 64 + blockIdx.x) * 4 + kc) * 64 + lane];
        }
        f4 dm = *(const f4*)(dls + t * 16 + 4 * q);
#pragma unroll
        for (int k = 0; k < 4; ++k) {
            float mm = dm[k];
            float ip = aX[0][k] + bg[0] + mm * aH[0][k];
            float fp = aX[1][k] + bg[1] + mm * aH[1][k];
            float gp = aX[2][k] + bg[2] + mm * aH[2][k];
            float op = aX[3][k] + bg[3] + mm * aH[3][k];
            float ii = sigf(ip), ff = sigf(fp), gg = tanhf_fast(gp), oo = sigf(op);
            float cc = ff * (mm * cst[k]) + ii * gg;
            cst[k] = cc;
            float hh = oo * tanhf_fast(cc);
            hn[(u >> 5) * 512 + (((u >> 3) & 3) * 16 + (4 * q + k)) * 8 + (u & 7)] = f2bf(hh);
        }
        __syncthreads();
        // write hs frags (overwrites this block's consumed hid3 chunk for step t)
        if (wv < 4) {
            u4 v = *(const u4*)(hn + wv * 512 + lane * 8);
            ((u4*)hws)[(((size_t)t * 64 + blockIdx.x) * 4 + wv) * 64 + lane] = v;
        }
    }
}

// ---------------- K4: heads (logits + value) ----------------
__global__ __launch_bounds__(256) void k4_heads(
    const u16* __restrict__ hsf, const u16* __restrict__ wf,
    const float* __restrict__ ba, const float* __restrict__ bc, float* __restrict__ out) {
    int tid = threadIdx.x, wv = tid >> 6, lane = tid & 63;
    int m = lane & 15, q = lane >> 4;
    int wid = blockIdx.x * 4 + wv;
    const short8* WAv = (const short8*)(wf + OFF_WA);
    short8 wab[2][4];
#pragma unroll
    for (int nt = 0; nt < 2; ++nt)
#pragma unroll
        for (int kc = 0; kc < 4; ++kc) wab[nt][kc] = WAv[(nt * 4 + kc) * 64 + lane];
    const short8* A = (const short8*)hsf;
    for (int it = 0; it < 8; ++it) {
        int c = wid + it * 2048;
        short8 a[4];
#pragma unroll
        for (int kc = 0; kc < 4; ++kc) a[kc] = A[((size_t)c * 4 + kc) * 64 + lane];
#pragma unroll
        for (int nt = 0; nt < 2; ++nt) {
            f4 acc = {0.f, 0.f, 0.f, 0.f};
#pragma unroll
            for (int kc = 0; kc < 4; ++kc) acc = MFMA(a[kc], wab[nt][kc], acc);
            int col = nt * 16 + m;
            if (col < 19) {
                float bb = (col < 18) ? ba[col] : bc[0];
#pragma unroll
                for (int p = 0; p < 4; ++p)
                    out[(size_t)(c * 16 + q * 4 + p) * 19 + col] = acc[p] + bb;
            }
        }
    }
}

extern "C" void kernel_launch(void* const* d_in, const int* in_sizes, int n_in,
                              void* d_out, int out_size, void* d_ws, size_t ws_size,
                              hipStream_t stream) {
    const float* x    = (const float*)d_in[0];
    const float* done = (const float*)d_in[1];
    const float* h0   = (const float*)d_in[2];
    const float* c0   = (const float*)d_in[3];
    const float* W1   = (const float*)d_in[4];
    const float* b1   = (const float*)d_in[5];
    const float* W2   = (const float*)d_in[6];
    const float* b2   = (const float*)d_in[7];
    const float* W3   = (const float*)d_in[8];
    const float* b3   = (const float*)d_in[9];
    const float* Wih  = (const float*)d_in[10];
    const float* Whh  = (const float*)d_in[11];
    const float* bih  = (const float*)d_in[12];
    const float* bhh  = (const float*)d_in[13];
    const float* Wa   = (const float*)d_in[14];
    const float* ba   = (const float*)d_in[15];
    const float* Wc   = (const float*)d_in[16];
    const float* bc   = (const float*)d_in[17];
    float* out = (float*)d_out;

    u16* ws = (u16*)d_ws;
    u16* hid3f = ws + WS_HID3;   // 67.1 MB, reused as hs after consumption
    u16* wf    = ws + WS_WF;     // 312 KB converted weights
    // total ws needed: (33554432 + 159744) * 2 = 67,428,352 bytes

    hipLaunchKernelGGL(k0_conv, dim3(128), dim3(256), 0, stream,
                       W1, W2, W3, Wih, Whh, Wa, Wc, wf);
    hipLaunchKernelGGL(k1_enc, dim3(512), dim3(256), 0, stream,
                       x, b1, b2, b3, wf, hid3f);
    hipLaunchKernelGGL(k3_lstm, dim3(64), dim3(512), 0, stream,
                       hid3f, wf, bih, bhh, done, h0, c0);
    hipLaunchKernelGGL(k4_heads, dim3(512), dim3(256), 0, stream,
                       hid3f, wf, ba, bc, out);
}